// Round 1
// baseline (349.246 us; speedup 1.0000x reference)
//
#include <hip/hip_runtime.h>

// Problem constants (fixed by setup_inputs):
//   T=16384 tokens, H=3072 hidden, E=64 experts, capacity=256
//   dispatch size = E*cap = 16384 (already a multiple of 256)
#define T_TOKENS 16384
#define HIDDEN   3072
#define NEXP     64
#define CAP      256
#define BLK      256
#define NGB      (T_TOKENS / BLK)      // 64 gating blocks
#define DSIZE    (NEXP * CAP)          // 16384 dispatch rows

// ---------------------------------------------------------------------------
// K1: per-token gating. One thread = one token (contiguous 256-token blocks so
// the ordered-cumsum decomposes into block-local rank + cross-block scan).
// ---------------------------------------------------------------------------
__global__ __launch_bounds__(BLK) void gate_kernel(
    const float* __restrict__ logits,
    int* __restrict__ expertOut, int* __restrict__ rankOut,
    float* __restrict__ scoreOut, int* __restrict__ blockCounts) {
  __shared__ int eLds[BLK];
  __shared__ int hist[NEXP];

  const int t = blockIdx.x * BLK + threadIdx.x;

  // Load this token's 64 logits (contiguous 256B per thread) as float4.
  const float4* lg = (const float4*)(logits + (size_t)t * NEXP);
  float l[NEXP];
#pragma unroll
  for (int i = 0; i < NEXP / 4; ++i) {
    float4 v = lg[i];
    l[4 * i + 0] = v.x; l[4 * i + 1] = v.y;
    l[4 * i + 2] = v.z; l[4 * i + 3] = v.w;
  }

  // First-occurrence argmax (matches jnp.argmax) + max.
  float mx = l[0];
  int arg = 0;
#pragma unroll
  for (int i = 1; i < NEXP; ++i) {
    if (l[i] > mx) { mx = l[i]; arg = i; }
  }
  // Softmax prob at argmax = 1 / sum(exp(l - mx)).
  float s = 0.f;
#pragma unroll
  for (int i = 0; i < NEXP; ++i) s += __expf(l[i] - mx);
  const float score = 1.0f / s;

  eLds[threadIdx.x] = arg;
  if (threadIdx.x < NEXP) hist[threadIdx.x] = 0;
  __syncthreads();

  // Ordered within-block rank: count of earlier tokens in this block with the
  // same expert. j is wave-uniform -> LDS broadcast read each iteration.
  int r = 0;
  const int tid = (int)threadIdx.x;
  for (int j = 0; j < BLK; ++j) {
    int ej = eLds[j];
    if (j < tid && ej == arg) ++r;
  }
  atomicAdd(&hist[arg], 1);
  __syncthreads();

  expertOut[t] = arg;
  rankOut[t]   = r;
  scoreOut[t]  = score;
  if (threadIdx.x < NEXP)
    blockCounts[blockIdx.x * NEXP + threadIdx.x] = hist[threadIdx.x];
}

// ---------------------------------------------------------------------------
// K2: per-expert exclusive scan across the 64 gating blocks (in-place),
// totals, and the expert_counts output (as float).
// ---------------------------------------------------------------------------
__global__ void scan_kernel(int* __restrict__ base, int* __restrict__ totals,
                            float* __restrict__ countsOut) {
  const int e = threadIdx.x;  // 64 threads
  int run = 0;
  for (int b = 0; b < NGB; ++b) {
    int c = base[b * NEXP + e];
    base[b * NEXP + e] = run;
    run += c;
  }
  totals[e] = run;
  countsOut[e] = (float)min(run, CAP);
}

// ---------------------------------------------------------------------------
// K3: block i does (a) token i's dispatch: metadata + scaled row copy if kept,
// and (b) slot-row i: zero-fill iff that slot is unfilled. Disjoint rows.
// (T_TOKENS == DSIZE == 16384 so one grid covers both roles.)
// ---------------------------------------------------------------------------
__global__ __launch_bounds__(BLK) void scatter_kernel(
    const float* __restrict__ act,
    const int* __restrict__ expert, const int* __restrict__ rank,
    const float* __restrict__ score,
    const int* __restrict__ base, const int* __restrict__ totals,
    float* __restrict__ moe, float* __restrict__ scoreOut,
    float* __restrict__ assignOut, float* __restrict__ slotsOut) {
  const int i = blockIdx.x;

  // ---- token role ----
  const int e   = expert[i];
  const int r   = rank[i];
  const int b   = i >> 8;  // i / BLK
  const int loc = base[b * NEXP + e] + r;
  const bool keep = loc < CAP;
  const float s = score[i];

  if (threadIdx.x == 0) {
    scoreOut[i]  = keep ? s : 0.0f;
    assignOut[i] = (float)e;
    slotsOut[i]  = keep ? (float)(e * CAP + loc) : -1.0f;
  }

  if (keep) {
    const int slot = e * CAP + loc;
    const float4* src = (const float4*)(act + (size_t)i * HIDDEN);
    float4* dst = (float4*)(moe + (size_t)slot * HIDDEN);
#pragma unroll
    for (int k = threadIdx.x; k < HIDDEN / 4; k += BLK) {
      float4 v = src[k];
      v.x *= s; v.y *= s; v.z *= s; v.w *= s;
      dst[k] = v;
    }
  }

  // ---- slot role: zero unfilled rows ----
  const int se = i / CAP;
  const int sp = i & (CAP - 1);
  const int kcnt = min(totals[se], CAP);
  if (sp >= kcnt) {
    float4* dst = (float4*)(moe + (size_t)i * HIDDEN);
    const float4 z = make_float4(0.f, 0.f, 0.f, 0.f);
#pragma unroll
    for (int k = threadIdx.x; k < HIDDEN / 4; k += BLK) dst[k] = z;
  }
}

// ---------------------------------------------------------------------------
extern "C" void kernel_launch(void* const* d_in, const int* in_sizes, int n_in,
                              void* d_out, int out_size, void* d_ws, size_t ws_size,
                              hipStream_t stream) {
  const float* act    = (const float*)d_in[0];
  const float* logits = (const float*)d_in[1];
  // d_in[2] is capacity==256, fixed; baked in as CAP.

  float* out       = (float*)d_out;
  float* moe       = out;                                  // [DSIZE*HIDDEN]
  float* scoreOut  = out + (size_t)DSIZE * HIDDEN;         // [T]
  float* assignOut = scoreOut + T_TOKENS;                  // [T] (int as float)
  float* slotsOut  = assignOut + T_TOKENS;                 // [T] (int as float)
  float* countsOut = slotsOut + T_TOKENS;                  // [E] (int as float)

  int*   expert = (int*)d_ws;                              // [T]
  int*   rank   = expert + T_TOKENS;                       // [T]
  float* score  = (float*)(rank + T_TOKENS);               // [T]
  int*   base   = (int*)(score + T_TOKENS);                // [NGB*NEXP]
  int*   totals = base + NGB * NEXP;                       // [NEXP]

  gate_kernel<<<NGB, BLK, 0, stream>>>(logits, expert, rank, score, base);
  scan_kernel<<<1, NEXP, 0, stream>>>(base, totals, countsOut);
  scatter_kernel<<<T_TOKENS, BLK, 0, stream>>>(act, expert, rank, score, base,
                                               totals, moe, scoreOut, assignOut,
                                               slotsOut);
}